// Round 1
// baseline (89.997 us; speedup 1.0000x reference)
//
#include <hip/hip_runtime.h>
#include <hip/hip_bf16.h>
#include <stdint.h>

typedef __attribute__((ext_vector_type(8))) short short8;
typedef __attribute__((ext_vector_type(4))) float f32x4;

__device__ __forceinline__ unsigned int f2bf(float f) {
    unsigned int u = __float_as_uint(f);
    return (u + 0x7fffu + ((u >> 16) & 1u)) >> 16;   // RNE fp32 -> bf16
}

// ---- kernel 1: per-row squared norm (fp32, from original data) ----
__global__ void sq_kernel(const float* __restrict__ emb,
                          float* __restrict__ sq, int n) {
    int row = blockIdx.x * 4 + (threadIdx.x >> 6);
    int lane = threadIdx.x & 63;
    if (row >= n) return;
    float2 v = *reinterpret_cast<const float2*>(emb + (size_t)row * 128 + lane * 2);
    float p = v.x * v.x + v.y * v.y;
    #pragma unroll
    for (int off = 32; off > 0; off >>= 1) p += __shfl_down(p, off);
    if (lane == 0) sq[row] = p;
}

// ---- kernel 2: tiled bf16-MFMA gram + fused loss epilogue ----
__launch_bounds__(256, 2)
__global__ void loss_kernel(const float* __restrict__ emb,
                            const int* __restrict__ labels,
                            const float* __restrict__ sq,
                            float* __restrict__ accum, int nt) {
    __shared__ __align__(16) unsigned short As[128 * 128];
    __shared__ __align__(16) unsigned short Bs[128 * 128];
    __shared__ float Ssq[2][128];
    __shared__ int   Slab[2][128];
    __shared__ float wsum[4];

    // linear block id -> upper-triangular tile (bi, bj), bj >= bi
    int tt = blockIdx.x, bi = 0;
    while (tt >= nt - bi) { tt -= nt - bi; ++bi; }
    int bj = bi + tt;
    int rowBase = bi << 7, colBase = bj << 7;

    int t = threadIdx.x;
    // stage both 128x128 fp32 tiles as bf16 into LDS, XOR-swizzled
    #pragma unroll
    for (int half = 0; half < 2; ++half) {
        int base = half ? colBase : rowBase;
        unsigned short* dst = half ? Bs : As;
        #pragma unroll
        for (int it = 0; it < 8; ++it) {
            int si = it * 256 + t;          // 0..2047 16B-slots
            int r = si >> 4, c16 = si & 15; // row, 16B slot in row
            const float* src = emb + (size_t)(base + r) * 128 + c16 * 8;
            float4 f0 = *reinterpret_cast<const float4*>(src);
            float4 f1 = *reinterpret_cast<const float4*>(src + 4);
            uint4 wv;
            wv.x = f2bf(f0.x) | (f2bf(f0.y) << 16);
            wv.y = f2bf(f0.z) | (f2bf(f0.w) << 16);
            wv.z = f2bf(f1.x) | (f2bf(f1.y) << 16);
            wv.w = f2bf(f1.z) | (f2bf(f1.w) << 16);
            int byte = (r << 8) + (c16 << 4);
            byte ^= (r & 7) << 4;           // bank-conflict swizzle
            *reinterpret_cast<uint4*>(reinterpret_cast<char*>(dst) + byte) = wv;
        }
    }
    if (t < 128) {
        Ssq[0][t] = sq[rowBase + t];  Slab[0][t] = labels[rowBase + t];
    } else {
        int u = t - 128;
        Ssq[1][u] = sq[colBase + u];  Slab[1][u] = labels[colBase + u];
    }
    __syncthreads();

    int lane = t & 63, w = t >> 6;
    int wr = (w >> 1) << 6, wc = (w & 1) << 6;  // 64x64 quadrant per wave
    int fr = lane & 15, kg = lane >> 4;

    f32x4 acc[4][4];
    const f32x4 zero = {0.0f, 0.0f, 0.0f, 0.0f};
    #pragma unroll
    for (int m = 0; m < 4; ++m)
        #pragma unroll
        for (int n = 0; n < 4; ++n) acc[m][n] = zero;

    #pragma unroll
    for (int kk = 0; kk < 4; ++kk) {
        int koff2 = (kk * 32 + kg * 8) * 2;  // byte offset of this lane's k-chunk
        short8 a[4], b[4];
        #pragma unroll
        for (int m = 0; m < 4; ++m) {
            int r = wr + m * 16 + fr;
            int byte = (r << 8) + koff2;
            byte ^= (r & 7) << 4;
            a[m] = *reinterpret_cast<const short8*>(
                       reinterpret_cast<const char*>(As) + byte);
        }
        #pragma unroll
        for (int n = 0; n < 4; ++n) {
            int r = wc + n * 16 + fr;
            int byte = (r << 8) + koff2;
            byte ^= (r & 7) << 4;
            b[n] = *reinterpret_cast<const short8*>(
                       reinterpret_cast<const char*>(Bs) + byte);
        }
        #pragma unroll
        for (int m = 0; m < 4; ++m)
            #pragma unroll
            for (int n = 0; n < 4; ++n)
                acc[m][n] = __builtin_amdgcn_mfma_f32_16x16x32_bf16(
                                a[m], b[n], acc[m][n], 0, 0, 0);
    }

    // fused epilogue: C/D layout col=lane&15, row=(lane>>4)*4+reg
    float local = 0.0f;
    #pragma unroll
    for (int n = 0; n < 4; ++n) {
        int jc = wc + n * 16 + fr;
        int j  = colBase + jc;
        float sqj = Ssq[1][jc];
        int   labj = Slab[1][jc];
        #pragma unroll
        for (int m = 0; m < 4; ++m) {
            #pragma unroll
            for (int r4 = 0; r4 < 4; ++r4) {
                int ir = wr + m * 16 + kg * 4 + r4;
                int i  = rowBase + ir;
                if (j > i) {
                    float d2   = Ssq[0][ir] + sqj - 2.0f * acc[m][n][r4];
                    float dist = sqrtf(fmaxf(d2, 0.0f));
                    float ds   = sqrtf(dist + 1e-7f);
                    local += (Slab[0][ir] == labj) ? ds : fmaxf(1.0f - ds, 0.0f);
                }
            }
        }
    }
    #pragma unroll
    for (int off = 32; off > 0; off >>= 1) local += __shfl_down(local, off);
    if (lane == 0) wsum[w] = local;
    __syncthreads();
    if (t == 0) atomicAdd(accum, wsum[0] + wsum[1] + wsum[2] + wsum[3]);
}

// ---- kernel 3: scale and write scalar output ----
__global__ void finalize_kernel(const float* __restrict__ accum,
                                float* __restrict__ out, double inv_pairs) {
    out[0] = (float)((double)accum[0] * inv_pairs);
}

extern "C" void kernel_launch(void* const* d_in, const int* in_sizes, int n_in,
                              void* d_out, int out_size, void* d_ws, size_t ws_size,
                              hipStream_t stream) {
    const float* emb   = (const float*)d_in[0];
    const int*  labels = (const int*)d_in[1];
    int n  = in_sizes[1];          // 8192
    int nt = n >> 7;               // 128-row tiles

    float* accum = (float*)d_ws;
    float* sq    = (float*)((char*)d_ws + 256);

    hipMemsetAsync(accum, 0, sizeof(float), stream);
    sq_kernel<<<n / 4, 256, 0, stream>>>(emb, sq, n);

    int nblocks = nt * (nt + 1) / 2;   // upper-triangular tiles incl. diagonal
    loss_kernel<<<nblocks, 256, 0, stream>>>(emb, labels, sq, accum, nt);

    double inv_pairs = 2.0 / ((double)n * (double)(n - 1));
    finalize_kernel<<<1, 1, 0, stream>>>(accum, (float*)d_out, inv_pairs);
}

// Round 2
// 61.049 us; speedup vs baseline: 1.4742x; 1.4742x over previous
//
#include <hip/hip_runtime.h>
#include <hip/hip_bf16.h>
#include <stdint.h>

typedef __attribute__((ext_vector_type(8))) short short8;
typedef __attribute__((ext_vector_type(4))) float f32x4;

__device__ __forceinline__ unsigned int f2bf(float f) {
    unsigned int u = __float_as_uint(f);
    return (u + 0x7fffu + ((u >> 16) & 1u)) >> 16;   // RNE fp32 -> bf16
}

// ---- kernel 1: fp32 -> bf16 pre-swizzled matrix + per-row squared norms ----
// 16 rows per block; 16 threads per row, 8 elems (32B fp32 / 16B bf16) each.
// Swizzled layout: element (r,k), chunk c=k>>3 stored at byte
//   r*256 + ((c ^ (r&7))<<4) + (k&7)*2
__global__ void prep_kernel(const float* __restrict__ emb,
                            unsigned short* __restrict__ ebs,
                            float* __restrict__ sq, int n) {
    int t = threadIdx.x;
    int row = blockIdx.x * 16 + (t >> 4);
    int c   = t & 15;
    if (row >= n) return;
    const float* src = emb + (size_t)row * 128 + c * 8;
    float4 f0 = *reinterpret_cast<const float4*>(src);
    float4 f1 = *reinterpret_cast<const float4*>(src + 4);
    uint4 wv;
    wv.x = f2bf(f0.x) | (f2bf(f0.y) << 16);
    wv.y = f2bf(f0.z) | (f2bf(f0.w) << 16);
    wv.z = f2bf(f1.x) | (f2bf(f1.y) << 16);
    wv.w = f2bf(f1.z) | (f2bf(f1.w) << 16);
    int byte = row * 256 + ((c ^ (row & 7)) << 4);
    *reinterpret_cast<uint4*>(reinterpret_cast<char*>(ebs) + byte) = wv;
    // fused squared norm (fp32 from original data)
    float p = f0.x*f0.x + f0.y*f0.y + f0.z*f0.z + f0.w*f0.w
            + f1.x*f1.x + f1.y*f1.y + f1.z*f1.z + f1.w*f1.w;
    #pragma unroll
    for (int off = 1; off < 16; off <<= 1) p += __shfl_xor(p, off);
    if (c == 0) sq[row] = p;
}

// ---- kernel 2: tiled bf16-MFMA gram + fused loss epilogue ----
__launch_bounds__(256, 2)
__global__ void loss_kernel(const unsigned short* __restrict__ ebs,
                            const int* __restrict__ labels,
                            const float* __restrict__ sq,
                            float* __restrict__ accum, int nt) {
    __shared__ __align__(16) unsigned short As[128 * 128];
    __shared__ __align__(16) unsigned short Bs[128 * 128];
    __shared__ float Ssq[2][128];
    __shared__ int   Slab[2][128];
    __shared__ float wsum[4];

    // linear block id -> upper-triangular tile (bi, bj), bj >= bi
    int tt = blockIdx.x, bi = 0;
    while (tt >= nt - bi) { tt -= nt - bi; ++bi; }
    int bj = bi + tt;
    int rowBase = bi << 7, colBase = bj << 7;
    bool diag = (bi == bj);

    int t = threadIdx.x;
    // stage pre-swizzled bf16 tiles linearly via async global->LDS (16B/lane)
    {
        const char* gA = reinterpret_cast<const char*>(ebs) + (size_t)rowBase * 256;
        const char* gB = reinterpret_cast<const char*>(ebs) + (size_t)colBase * 256;
        int waveOff = (t >> 6) << 10;          // wave-uniform LDS offset
        int laneOff = (t & 63) << 4;           // lane slot (16B) within 1KB
        #pragma unroll
        for (int it = 0; it < 8; ++it) {
            int off = it * 4096 + waveOff;
            __builtin_amdgcn_global_load_lds(
                (const __attribute__((address_space(1))) void*)(gA + off + laneOff),
                (__attribute__((address_space(3))) void*)((char*)As + off), 16, 0, 0);
        }
        if (!diag) {
            #pragma unroll
            for (int it = 0; it < 8; ++it) {
                int off = it * 4096 + waveOff;
                __builtin_amdgcn_global_load_lds(
                    (const __attribute__((address_space(1))) void*)(gB + off + laneOff),
                    (__attribute__((address_space(3))) void*)((char*)Bs + off), 16, 0, 0);
            }
        }
    }
    if (t < 128) {
        Ssq[0][t] = sq[rowBase + t];  Slab[0][t] = labels[rowBase + t];
    } else {
        int u = t - 128;
        Ssq[1][u] = sq[colBase + u];  Slab[1][u] = labels[colBase + u];
    }
    __syncthreads();

    int lane = t & 63, w = t >> 6;
    int wr = (w >> 1) << 6, wc = (w & 1) << 6;  // 64x64 quadrant per wave
    int fr = lane & 15, kg = lane >> 4;
    const char* Ab = reinterpret_cast<const char*>(As);
    const char* Bb = diag ? Ab : reinterpret_cast<const char*>(Bs);

    f32x4 acc[4][4];
    const f32x4 zero = {0.0f, 0.0f, 0.0f, 0.0f};
    #pragma unroll
    for (int m = 0; m < 4; ++m)
        #pragma unroll
        for (int n = 0; n < 4; ++n) acc[m][n] = zero;

    #pragma unroll
    for (int kk = 0; kk < 4; ++kk) {
        int koff2 = kk * 64 + kg * 16;       // byte offset of this lane's k-chunk
        short8 a[4], b[4];
        #pragma unroll
        for (int m = 0; m < 4; ++m) {
            int r = wr + m * 16 + fr;
            int byte = (r << 8) + (koff2 ^ ((r & 7) << 4));
            a[m] = *reinterpret_cast<const short8*>(Ab + byte);
        }
        #pragma unroll
        for (int n = 0; n < 4; ++n) {
            int r = wc + n * 16 + fr;
            int byte = (r << 8) + (koff2 ^ ((r & 7) << 4));
            b[n] = *reinterpret_cast<const short8*>(Bb + byte);
        }
        #pragma unroll
        for (int m = 0; m < 4; ++m)
            #pragma unroll
            for (int n = 0; n < 4; ++n)
                acc[m][n] = __builtin_amdgcn_mfma_f32_16x16x32_bf16(
                                a[m], b[n], acc[m][n], 0, 0, 0);
    }

    // fused epilogue: C/D layout col=lane&15, row=(lane>>4)*4+reg
    bool offdiag = !diag;
    float local = 0.0f;
    #pragma unroll
    for (int n = 0; n < 4; ++n) {
        int jc = wc + n * 16 + fr;
        float sqj  = Ssq[1][jc];
        int   labj = Slab[1][jc];
        #pragma unroll
        for (int m = 0; m < 4; ++m) {
            #pragma unroll
            for (int r4 = 0; r4 < 4; ++r4) {
                int ir = wr + m * 16 + kg * 4 + r4;
                if (offdiag || jc > ir) {
                    float d2   = fmaf(-2.0f, acc[m][n][r4], Ssq[0][ir] + sqj);
                    float dist = __builtin_amdgcn_sqrtf(fmaxf(d2, 0.0f));
                    float ds   = __builtin_amdgcn_sqrtf(dist + 1e-7f);
                    local += (Slab[0][ir] == labj) ? ds : fmaxf(1.0f - ds, 0.0f);
                }
            }
        }
    }
    #pragma unroll
    for (int off = 32; off > 0; off >>= 1) local += __shfl_down(local, off);
    if (lane == 0) wsum[w] = local;
    __syncthreads();
    if (t == 0) atomicAdd(accum, wsum[0] + wsum[1] + wsum[2] + wsum[3]);
}

// ---- kernel 3: scale and write scalar output ----
__global__ void finalize_kernel(const float* __restrict__ accum,
                                float* __restrict__ out, double inv_pairs) {
    out[0] = (float)((double)accum[0] * inv_pairs);
}

extern "C" void kernel_launch(void* const* d_in, const int* in_sizes, int n_in,
                              void* d_out, int out_size, void* d_ws, size_t ws_size,
                              hipStream_t stream) {
    const float* emb   = (const float*)d_in[0];
    const int*  labels = (const int*)d_in[1];
    int n  = in_sizes[1];          // 8192
    int nt = n >> 7;               // 128-row tiles

    float*          accum = (float*)d_ws;
    float*          sq    = (float*)((char*)d_ws + 256);
    unsigned short* ebs   = (unsigned short*)((char*)d_ws + 65536);

    hipMemsetAsync(accum, 0, sizeof(float), stream);
    prep_kernel<<<n / 16, 256, 0, stream>>>(emb, ebs, sq, n);

    int nblocks = nt * (nt + 1) / 2;   // upper-triangular tiles incl. diagonal
    loss_kernel<<<nblocks, 256, 0, stream>>>(ebs, labels, sq, accum, nt);

    double inv_pairs = 2.0 / ((double)n * (double)(n - 1));
    finalize_kernel<<<1, 1, 0, stream>>>(accum, (float*)d_out, inv_pairs);
}